// Round 1
// baseline (2115.916 us; speedup 1.0000x reference)
//
#include <hip/hip_runtime.h>
#include <cstddef>

// ---------------- degree / norm ----------------
__global__ __launch_bounds__(256) void k_deg_init(int* __restrict__ deg, int n) {
    int i = blockIdx.x * 256 + threadIdx.x;
    if (i < n) deg[i] = 1;   // self-loop contributes 1
}

__global__ __launch_bounds__(256) void k_deg_count(const int* __restrict__ dst, int* __restrict__ deg, int e) {
    int i = blockIdx.x * 256 + threadIdx.x;
    if (i < e) atomicAdd(&deg[dst[i]], 1);
}

__global__ __launch_bounds__(256) void k_dinv(const int* __restrict__ deg, float* __restrict__ dinv, int n) {
    int i = blockIdx.x * 256 + threadIdx.x;
    if (i < n) dinv[i] = rsqrtf((float)deg[i]);   // deg >= 1 always
}

// ---------------- GEMM1: xw[M,128] = x[M,128] @ W[128,128] ----------------
__global__ __launch_bounds__(256) void k_gemm1(const float* __restrict__ x, const float* __restrict__ W,
                                               float* __restrict__ xw, int M) {
    __shared__ float ws[128 * 128];      // ws[k*128 + c]
    __shared__ float xs[128][32];        // xs[k][r]  (transposed tile)
    const int tid  = threadIdx.x;
    const int row0 = blockIdx.x * 32;

    for (int i = tid * 4; i < 128 * 128; i += 1024)
        *(float4*)&ws[i] = *(const float4*)&W[i];

    for (int i = tid; i < 32 * 32; i += 256) {
        int r  = i >> 5;
        int cc = (i & 31) << 2;
        float4 v = make_float4(0.f, 0.f, 0.f, 0.f);
        if (row0 + r < M) v = *(const float4*)&x[(size_t)(row0 + r) * 128 + cc];
        xs[cc + 0][r] = v.x; xs[cc + 1][r] = v.y; xs[cc + 2][r] = v.z; xs[cc + 3][r] = v.w;
    }
    __syncthreads();

    const int c0 = (tid & 31) << 2;      // 4 cols
    const int r0 = (tid >> 5) << 2;      // 4 rows
    float4 a0 = {0,0,0,0}, a1 = {0,0,0,0}, a2 = {0,0,0,0}, a3 = {0,0,0,0};
#pragma unroll 8
    for (int k = 0; k < 128; ++k) {
        float4 wv = *(const float4*)&ws[k * 128 + c0];
        float4 xv = *(const float4*)&xs[k][r0];
        a0.x += xv.x * wv.x; a0.y += xv.x * wv.y; a0.z += xv.x * wv.z; a0.w += xv.x * wv.w;
        a1.x += xv.y * wv.x; a1.y += xv.y * wv.y; a1.z += xv.y * wv.z; a1.w += xv.y * wv.w;
        a2.x += xv.z * wv.x; a2.y += xv.z * wv.y; a2.z += xv.z * wv.z; a2.w += xv.z * wv.w;
        a3.x += xv.w * wv.x; a3.y += xv.w * wv.y; a3.z += xv.w * wv.z; a3.w += xv.w * wv.w;
    }
    if (row0 + r0 + 0 < M) *(float4*)&xw[(size_t)(row0 + r0 + 0) * 128 + c0] = a0;
    if (row0 + r0 + 1 < M) *(float4*)&xw[(size_t)(row0 + r0 + 1) * 128 + c0] = a1;
    if (row0 + r0 + 2 < M) *(float4*)&xw[(size_t)(row0 + r0 + 2) * 128 + c0] = a2;
    if (row0 + r0 + 3 < M) *(float4*)&xw[(size_t)(row0 + r0 + 3) * 128 + c0] = a3;
}

// ---------------- GEMM2: hw[M,64] = relu(h[M,128]) @ W[128,64] ----------------
// h already includes b1 (folded into init1), so only relu here.
__global__ __launch_bounds__(256) void k_gemm2(const float* __restrict__ h_in, const float* __restrict__ W,
                                               float* __restrict__ hw, int M) {
    __shared__ float ws[128 * 64];       // ws[k*64 + c]
    __shared__ float xs[128][32];        // xs[k][r]
    const int tid  = threadIdx.x;
    const int row0 = blockIdx.x * 32;

    for (int i = tid * 4; i < 128 * 64; i += 1024)
        *(float4*)&ws[i] = *(const float4*)&W[i];

    for (int i = tid; i < 32 * 32; i += 256) {
        int r  = i >> 5;
        int cc = (i & 31) << 2;
        float4 v = make_float4(0.f, 0.f, 0.f, 0.f);
        if (row0 + r < M) {
            v = *(const float4*)&h_in[(size_t)(row0 + r) * 128 + cc];
            v.x = fmaxf(v.x, 0.f); v.y = fmaxf(v.y, 0.f);
            v.z = fmaxf(v.z, 0.f); v.w = fmaxf(v.w, 0.f);
        }
        xs[cc + 0][r] = v.x; xs[cc + 1][r] = v.y; xs[cc + 2][r] = v.z; xs[cc + 3][r] = v.w;
    }
    __syncthreads();

    const int c0 = (tid & 15) << 2;      // 4 cols of 64
    const int r0 = (tid >> 4) << 1;      // 2 rows
    float4 a0 = {0,0,0,0}, a1 = {0,0,0,0};
#pragma unroll 8
    for (int k = 0; k < 128; ++k) {
        float4 wv = *(const float4*)&ws[k * 64 + c0];
        float2 xv = *(const float2*)&xs[k][r0];
        a0.x += xv.x * wv.x; a0.y += xv.x * wv.y; a0.z += xv.x * wv.z; a0.w += xv.x * wv.w;
        a1.x += xv.y * wv.x; a1.y += xv.y * wv.y; a1.z += xv.y * wv.z; a1.w += xv.y * wv.w;
    }
    if (row0 + r0 + 0 < M) *(float4*)&hw[(size_t)(row0 + r0 + 0) * 64 + c0] = a0;
    if (row0 + r0 + 1 < M) *(float4*)&hw[(size_t)(row0 + r0 + 1) * 64 + c0] = a1;
}

// ---------------- init: out = bias + self_loop (xw * dinv^2) ----------------
__global__ __launch_bounds__(256) void k_init1(const float* __restrict__ xw, const float* __restrict__ dinv,
                                               const float* __restrict__ b, float* __restrict__ out1, int N) {
    int idx = blockIdx.x * 256 + threadIdx.x;     // one float4 per thread, 32 per node
    if (idx >= N * 32) return;
    int node = idx >> 5;
    int j    = (idx & 31) << 2;
    float di = dinv[node];
    float w  = di * di;
    float4 v  = *(const float4*)&xw[(size_t)idx * 4];
    float4 bb = *(const float4*)&b[j];
    *(float4*)&out1[(size_t)idx * 4] =
        make_float4(bb.x + v.x * w, bb.y + v.y * w, bb.z + v.z * w, bb.w + v.w * w);
}

__global__ __launch_bounds__(256) void k_init2(const float* __restrict__ hw, const float* __restrict__ dinv,
                                               const float* __restrict__ b, float* __restrict__ out, int N) {
    int idx = blockIdx.x * 256 + threadIdx.x;     // one float4 per thread, 16 per node
    if (idx >= N * 16) return;
    int node = idx >> 4;
    int j    = (idx & 15) << 2;
    float di = dinv[node];
    float w  = di * di;
    float4 v  = *(const float4*)&hw[(size_t)idx * 4];
    float4 bb = *(const float4*)&b[j];
    *(float4*)&out[(size_t)idx * 4] =
        make_float4(bb.x + v.x * w, bb.y + v.y * w, bb.z + v.z * w, bb.w + v.w * w);
}

// ---------------- edge scatter: out[dst] += xw[src] * dinv[s]*dinv[d] ----------------
// layer1: 128 cols, one 64-lane wave per edge, float2 per lane
__global__ __launch_bounds__(256) void k_scatter1(const int* __restrict__ src, const int* __restrict__ dst,
                                                  const float* __restrict__ dinv, const float* __restrict__ xw,
                                                  float* __restrict__ out1, int E) {
    const int lane = threadIdx.x & 63;
    const int nG   = gridDim.x * 4;
    int g = blockIdx.x * 4 + (threadIdx.x >> 6);
    for (int e = g; e < E; e += nG) {
        int s = src[e], d = dst[e];
        float w = dinv[s] * dinv[d];
        float2 v = *(const float2*)&xw[(size_t)s * 128 + lane * 2];
        float* o = &out1[(size_t)d * 128 + lane * 2];
        unsafeAtomicAdd(o,     v.x * w);
        unsafeAtomicAdd(o + 1, v.y * w);
    }
}

// layer2: 64 cols, one 32-lane half-wave per edge, float2 per lane
__global__ __launch_bounds__(256) void k_scatter2(const int* __restrict__ src, const int* __restrict__ dst,
                                                  const float* __restrict__ dinv, const float* __restrict__ hw,
                                                  float* __restrict__ out, int E) {
    const int lane = threadIdx.x & 31;
    const int nG   = gridDim.x * 8;
    int g = blockIdx.x * 8 + (threadIdx.x >> 5);
    for (int e = g; e < E; e += nG) {
        int s = src[e], d = dst[e];
        float w = dinv[s] * dinv[d];
        float2 v = *(const float2*)&hw[(size_t)s * 64 + lane * 2];
        float* o = &out[(size_t)d * 64 + lane * 2];
        unsafeAtomicAdd(o,     v.x * w);
        unsafeAtomicAdd(o + 1, v.y * w);
    }
}

extern "C" void kernel_launch(void* const* d_in, const int* in_sizes, int n_in,
                              void* d_out, int out_size, void* d_ws, size_t ws_size,
                              hipStream_t stream) {
    const float* x  = (const float*)d_in[0];
    const int*   ei = (const int*)  d_in[1];
    const float* W1 = (const float*)d_in[2];
    const float* b1 = (const float*)d_in[3];
    const float* W2 = (const float*)d_in[4];
    const float* b2 = (const float*)d_in[5];
    float* out = (float*)d_out;

    const int N = in_sizes[0] / 128;   // 50000
    const int E = in_sizes[1] / 2;     // 1600000
    const int* src = ei;
    const int* dst = ei + E;

    // workspace layout (floats): deg[N] | dinv[N] | xw[N*128] | out1[N*128]
    int*   deg  = (int*)d_ws;
    float* dinv = (float*)d_ws + N;
    float* xw   = (float*)d_ws + 2 * (size_t)N;
    float* out1 = xw + (size_t)N * 128;
    float* hw   = xw;   // alias: xw is dead once gemm2 runs

    k_deg_init <<<(N + 255) / 256, 256, 0, stream>>>(deg, N);
    k_deg_count<<<(E + 255) / 256, 256, 0, stream>>>(dst, deg, E);
    k_dinv     <<<(N + 255) / 256, 256, 0, stream>>>(deg, dinv, N);

    k_gemm1    <<<(N + 31) / 32, 256, 0, stream>>>(x, W1, xw, N);
    k_init1    <<<(N * 32 + 255) / 256, 256, 0, stream>>>(xw, dinv, b1, out1, N);
    k_scatter1 <<<2048, 256, 0, stream>>>(src, dst, dinv, xw, out1, E);

    k_gemm2    <<<(N + 31) / 32, 256, 0, stream>>>(out1, W2, hw, N);
    k_init2    <<<(N * 16 + 255) / 256, 256, 0, stream>>>(hw, dinv, b2, out, N);
    k_scatter2 <<<2048, 256, 0, stream>>>(src, dst, dinv, hw, out, E);
}

// Round 2
// 388.649 us; speedup vs baseline: 5.4443x; 5.4443x over previous
//
#include <hip/hip_runtime.h>
#include <cstddef>

// ---------------- degree / norm ----------------
__global__ __launch_bounds__(256) void k_deg_init(int* __restrict__ deg, int n) {
    int i = blockIdx.x * 256 + threadIdx.x;
    if (i < n) deg[i] = 1;   // self-loop contributes 1
}

__global__ __launch_bounds__(256) void k_deg_count(const int* __restrict__ dst, int* __restrict__ deg, int e) {
    int i = blockIdx.x * 256 + threadIdx.x;
    if (i < e) atomicAdd(&deg[dst[i]], 1);
}

__global__ __launch_bounds__(256) void k_dinv(const int* __restrict__ deg, float* __restrict__ dinv, int n) {
    int i = blockIdx.x * 256 + threadIdx.x;
    if (i < n) dinv[i] = rsqrtf((float)deg[i]);   // deg >= 1 always
}

// ---------------- exclusive scan of edge-counts (deg-1) over N ----------------
__global__ __launch_bounds__(256) void k_scan1(const int* __restrict__ deg, int* __restrict__ off,
                                               int* __restrict__ partial, int N) {
    __shared__ int sh[256];
    int i = blockIdx.x * 256 + threadIdx.x;
    int v = (i < N) ? (deg[i] - 1) : 0;
    sh[threadIdx.x] = v;
    __syncthreads();
    for (int d = 1; d < 256; d <<= 1) {
        int t = (threadIdx.x >= d) ? sh[threadIdx.x - d] : 0;
        __syncthreads();
        sh[threadIdx.x] += t;
        __syncthreads();
    }
    if (i < N) off[i] = sh[threadIdx.x] - v;           // exclusive
    if (threadIdx.x == 255) partial[blockIdx.x] = sh[255];
}

__global__ __launch_bounds__(256) void k_scan2(int* __restrict__ partial, int nb) {
    __shared__ int sh[256];
    int v = (threadIdx.x < nb) ? partial[threadIdx.x] : 0;
    sh[threadIdx.x] = v;
    __syncthreads();
    for (int d = 1; d < 256; d <<= 1) {
        int t = (threadIdx.x >= d) ? sh[threadIdx.x - d] : 0;
        __syncthreads();
        sh[threadIdx.x] += t;
        __syncthreads();
    }
    if (threadIdx.x < nb) partial[threadIdx.x] = sh[threadIdx.x] - v;  // exclusive
}

__global__ __launch_bounds__(256) void k_scan3(int* __restrict__ off, const int* __restrict__ partial,
                                               int* __restrict__ cursor, int N) {
    int i = blockIdx.x * 256 + threadIdx.x;
    if (i < N) {
        int o = off[i] + partial[blockIdx.x];
        off[i] = o;
        cursor[i] = o;
    }
}

// ---------------- bucket edges by dst: epack[p] = {src, w} ----------------
__global__ __launch_bounds__(256) void k_bucket(const int* __restrict__ src, const int* __restrict__ dst,
                                                const float* __restrict__ dinv, int* __restrict__ cursor,
                                                int2* __restrict__ epack, int E) {
    int e = blockIdx.x * 256 + threadIdx.x;
    if (e >= E) return;
    int s = src[e], d = dst[e];
    float w = dinv[s] * dinv[d];
    int p = atomicAdd(&cursor[d], 1);
    epack[p] = make_int2(s, __float_as_int(w));
}

// ---------------- GEMM1: xw[M,128] = x[M,128] @ W[128,128] ----------------
__global__ __launch_bounds__(256) void k_gemm1(const float* __restrict__ x, const float* __restrict__ W,
                                               float* __restrict__ xw, int M) {
    __shared__ float ws[128 * 128];      // ws[k*128 + c]
    __shared__ float xs[128][32];        // xs[k][r]  (transposed tile)
    const int tid  = threadIdx.x;
    const int row0 = blockIdx.x * 32;

    for (int i = tid * 4; i < 128 * 128; i += 1024)
        *(float4*)&ws[i] = *(const float4*)&W[i];

    for (int i = tid; i < 32 * 32; i += 256) {
        int r  = i >> 5;
        int cc = (i & 31) << 2;
        float4 v = make_float4(0.f, 0.f, 0.f, 0.f);
        if (row0 + r < M) v = *(const float4*)&x[(size_t)(row0 + r) * 128 + cc];
        xs[cc + 0][r] = v.x; xs[cc + 1][r] = v.y; xs[cc + 2][r] = v.z; xs[cc + 3][r] = v.w;
    }
    __syncthreads();

    const int c0 = (tid & 31) << 2;      // 4 cols
    const int r0 = (tid >> 5) << 2;      // 4 rows
    float4 a0 = {0,0,0,0}, a1 = {0,0,0,0}, a2 = {0,0,0,0}, a3 = {0,0,0,0};
#pragma unroll 8
    for (int k = 0; k < 128; ++k) {
        float4 wv = *(const float4*)&ws[k * 128 + c0];
        float4 xv = *(const float4*)&xs[k][r0];
        a0.x += xv.x * wv.x; a0.y += xv.x * wv.y; a0.z += xv.x * wv.z; a0.w += xv.x * wv.w;
        a1.x += xv.y * wv.x; a1.y += xv.y * wv.y; a1.z += xv.y * wv.z; a1.w += xv.y * wv.w;
        a2.x += xv.z * wv.x; a2.y += xv.z * wv.y; a2.z += xv.z * wv.z; a2.w += xv.z * wv.w;
        a3.x += xv.w * wv.x; a3.y += xv.w * wv.y; a3.z += xv.w * wv.z; a3.w += xv.w * wv.w;
    }
    if (row0 + r0 + 0 < M) *(float4*)&xw[(size_t)(row0 + r0 + 0) * 128 + c0] = a0;
    if (row0 + r0 + 1 < M) *(float4*)&xw[(size_t)(row0 + r0 + 1) * 128 + c0] = a1;
    if (row0 + r0 + 2 < M) *(float4*)&xw[(size_t)(row0 + r0 + 2) * 128 + c0] = a2;
    if (row0 + r0 + 3 < M) *(float4*)&xw[(size_t)(row0 + r0 + 3) * 128 + c0] = a3;
}

// ---------------- GEMM2: hw[M,64] = relu(h[M,128]) @ W[128,64] ----------------
__global__ __launch_bounds__(256) void k_gemm2(const float* __restrict__ h_in, const float* __restrict__ W,
                                               float* __restrict__ hw, int M) {
    __shared__ float ws[128 * 64];       // ws[k*64 + c]
    __shared__ float xs[128][32];        // xs[k][r]
    const int tid  = threadIdx.x;
    const int row0 = blockIdx.x * 32;

    for (int i = tid * 4; i < 128 * 64; i += 1024)
        *(float4*)&ws[i] = *(const float4*)&W[i];

    for (int i = tid; i < 32 * 32; i += 256) {
        int r  = i >> 5;
        int cc = (i & 31) << 2;
        float4 v = make_float4(0.f, 0.f, 0.f, 0.f);
        if (row0 + r < M) {
            v = *(const float4*)&h_in[(size_t)(row0 + r) * 128 + cc];
            v.x = fmaxf(v.x, 0.f); v.y = fmaxf(v.y, 0.f);
            v.z = fmaxf(v.z, 0.f); v.w = fmaxf(v.w, 0.f);
        }
        xs[cc + 0][r] = v.x; xs[cc + 1][r] = v.y; xs[cc + 2][r] = v.z; xs[cc + 3][r] = v.w;
    }
    __syncthreads();

    const int c0 = (tid & 15) << 2;      // 4 cols of 64
    const int r0 = (tid >> 4) << 1;      // 2 rows
    float4 a0 = {0,0,0,0}, a1 = {0,0,0,0};
#pragma unroll 8
    for (int k = 0; k < 128; ++k) {
        float4 wv = *(const float4*)&ws[k * 64 + c0];
        float2 xv = *(const float2*)&xs[k][r0];
        a0.x += xv.x * wv.x; a0.y += xv.x * wv.y; a0.z += xv.x * wv.z; a0.w += xv.x * wv.w;
        a1.x += xv.y * wv.x; a1.y += xv.y * wv.y; a1.z += xv.y * wv.z; a1.w += xv.y * wv.w;
    }
    if (row0 + r0 + 0 < M) *(float4*)&hw[(size_t)(row0 + r0 + 0) * 64 + c0] = a0;
    if (row0 + r0 + 1 < M) *(float4*)&hw[(size_t)(row0 + r0 + 1) * 64 + c0] = a1;
}

// ---------------- pull aggregation, layer1: 128 cols, one wave per node ----------------
__global__ __launch_bounds__(256) void k_agg1(const float* __restrict__ xw, const int2* __restrict__ epack,
                                              const int* __restrict__ off, const int* __restrict__ deg,
                                              const float* __restrict__ dinv, const float* __restrict__ b,
                                              float* __restrict__ out1, int N) {
    const int node = blockIdx.x * 4 + (threadIdx.x >> 6);
    if (node >= N) return;
    const int lane = threadIdx.x & 63;

    float di = dinv[node];
    float w0 = di * di;
    float2 xv = *(const float2*)&xw[(size_t)node * 128 + lane * 2];
    float2 bb = *(const float2*)&b[lane * 2];
    float2 acc = make_float2(bb.x + xv.x * w0, bb.y + xv.y * w0);

    const int base = off[node];
    const int end  = base + deg[node] - 1;
    for (int p = base; p < end; p += 64) {
        int2 ep = make_int2(0, 0);
        if (p + lane < end) ep = epack[p + lane];
        const int take = min(64, end - p);
        int j = 0;
        for (; j + 4 <= take; j += 4) {
            int   s0 = __shfl(ep.x, j + 0); float w0f = __int_as_float(__shfl(ep.y, j + 0));
            int   s1 = __shfl(ep.x, j + 1); float w1f = __int_as_float(__shfl(ep.y, j + 1));
            int   s2 = __shfl(ep.x, j + 2); float w2f = __int_as_float(__shfl(ep.y, j + 2));
            int   s3 = __shfl(ep.x, j + 3); float w3f = __int_as_float(__shfl(ep.y, j + 3));
            float2 v0 = *(const float2*)&xw[(size_t)s0 * 128 + lane * 2];
            float2 v1 = *(const float2*)&xw[(size_t)s1 * 128 + lane * 2];
            float2 v2 = *(const float2*)&xw[(size_t)s2 * 128 + lane * 2];
            float2 v3 = *(const float2*)&xw[(size_t)s3 * 128 + lane * 2];
            acc.x += v0.x * w0f; acc.y += v0.y * w0f;
            acc.x += v1.x * w1f; acc.y += v1.y * w1f;
            acc.x += v2.x * w2f; acc.y += v2.y * w2f;
            acc.x += v3.x * w3f; acc.y += v3.y * w3f;
        }
        for (; j < take; ++j) {
            int   s = __shfl(ep.x, j);
            float w = __int_as_float(__shfl(ep.y, j));
            float2 v = *(const float2*)&xw[(size_t)s * 128 + lane * 2];
            acc.x += v.x * w; acc.y += v.y * w;
        }
    }
    *(float2*)&out1[(size_t)node * 128 + lane * 2] = acc;
}

// ---------------- pull aggregation, layer2: 64 cols, half-wave per node ----------------
__global__ __launch_bounds__(256) void k_agg2(const float* __restrict__ hw, const int2* __restrict__ epack,
                                              const int* __restrict__ off, const int* __restrict__ deg,
                                              const float* __restrict__ dinv, const float* __restrict__ b,
                                              float* __restrict__ out, int N) {
    const int node = blockIdx.x * 8 + (threadIdx.x >> 5);
    if (node >= N) return;
    const int lane = threadIdx.x & 31;

    float di = dinv[node];
    float w0 = di * di;
    float2 xv = *(const float2*)&hw[(size_t)node * 64 + lane * 2];
    float2 bb = *(const float2*)&b[lane * 2];
    float2 acc = make_float2(bb.x + xv.x * w0, bb.y + xv.y * w0);

    const int base = off[node];
    const int end  = base + deg[node] - 1;
    for (int p = base; p < end; p += 32) {
        int2 ep = make_int2(0, 0);
        if (p + lane < end) ep = epack[p + lane];
        const int take = min(32, end - p);
        int j = 0;
        for (; j + 4 <= take; j += 4) {
            int   s0 = __shfl(ep.x, j + 0, 32); float w0f = __int_as_float(__shfl(ep.y, j + 0, 32));
            int   s1 = __shfl(ep.x, j + 1, 32); float w1f = __int_as_float(__shfl(ep.y, j + 1, 32));
            int   s2 = __shfl(ep.x, j + 2, 32); float w2f = __int_as_float(__shfl(ep.y, j + 2, 32));
            int   s3 = __shfl(ep.x, j + 3, 32); float w3f = __int_as_float(__shfl(ep.y, j + 3, 32));
            float2 v0 = *(const float2*)&hw[(size_t)s0 * 64 + lane * 2];
            float2 v1 = *(const float2*)&hw[(size_t)s1 * 64 + lane * 2];
            float2 v2 = *(const float2*)&hw[(size_t)s2 * 64 + lane * 2];
            float2 v3 = *(const float2*)&hw[(size_t)s3 * 64 + lane * 2];
            acc.x += v0.x * w0f; acc.y += v0.y * w0f;
            acc.x += v1.x * w1f; acc.y += v1.y * w1f;
            acc.x += v2.x * w2f; acc.y += v2.y * w2f;
            acc.x += v3.x * w3f; acc.y += v3.y * w3f;
        }
        for (; j < take; ++j) {
            int   s = __shfl(ep.x, j, 32);
            float w = __int_as_float(__shfl(ep.y, j, 32));
            float2 v = *(const float2*)&hw[(size_t)s * 64 + lane * 2];
            acc.x += v.x * w; acc.y += v.y * w;
        }
    }
    *(float2*)&out[(size_t)node * 64 + lane * 2] = acc;
}

extern "C" void kernel_launch(void* const* d_in, const int* in_sizes, int n_in,
                              void* d_out, int out_size, void* d_ws, size_t ws_size,
                              hipStream_t stream) {
    const float* x  = (const float*)d_in[0];
    const int*   ei = (const int*)  d_in[1];
    const float* W1 = (const float*)d_in[2];
    const float* b1 = (const float*)d_in[3];
    const float* W2 = (const float*)d_in[4];
    const float* b2 = (const float*)d_in[5];
    float* out = (float*)d_out;

    const int N = in_sizes[0] / 128;   // 50000
    const int E = in_sizes[1] / 2;     // 1600000
    const int* src = ei;
    const int* dst = ei + E;
    const int NB = (N + 255) / 256;    // scan blocks (196)

    // workspace layout:
    // deg[N] int | dinv[N] f32 | off[N] int | cursor[N] int | partial[256] int |
    // epack[E] int2 | xw[N*128] f32 | out1[N*128] f32
    char* w = (char*)d_ws;
    int*   deg     = (int*)w;                 w += (size_t)N * 4;
    float* dinv    = (float*)w;               w += (size_t)N * 4;
    int*   off     = (int*)w;                 w += (size_t)N * 4;
    int*   cursor  = (int*)w;                 w += (size_t)N * 4;
    int*   partial = (int*)w;                 w += 256 * 4;
    int2*  epack   = (int2*)w;                w += (size_t)E * 8;
    float* xw      = (float*)w;               w += (size_t)N * 128 * 4;
    float* out1    = (float*)w;
    float* hw      = xw;   // alias: xw dead after gemm2 consumes out1

    // --- graph preprocessing (every call; deterministic workload) ---
    k_deg_init <<<NB, 256, 0, stream>>>(deg, N);
    k_deg_count<<<(E + 255) / 256, 256, 0, stream>>>(dst, deg, E);
    k_dinv     <<<NB, 256, 0, stream>>>(deg, dinv, N);
    k_scan1    <<<NB, 256, 0, stream>>>(deg, off, partial, N);
    k_scan2    <<<1, 256, 0, stream>>>(partial, NB);
    k_scan3    <<<NB, 256, 0, stream>>>(off, partial, cursor, N);
    k_bucket   <<<(E + 255) / 256, 256, 0, stream>>>(src, dst, dinv, cursor, epack, E);

    // --- layer 1 ---
    k_gemm1 <<<(N + 31) / 32, 256, 0, stream>>>(x, W1, xw, N);
    k_agg1  <<<(N + 3) / 4, 256, 0, stream>>>(xw, epack, off, deg, dinv, b1, out1, N);

    // --- layer 2 ---
    k_gemm2 <<<(N + 31) / 32, 256, 0, stream>>>(out1, W2, hw, N);
    k_agg2  <<<(N + 7) / 8, 256, 0, stream>>>(hw, epack, off, deg, dinv, b2, out, N);
}